// Round 1
// baseline (64.628 us; speedup 1.0000x reference)
//
#include <hip/hip_runtime.h>

#define B_N 256
#define B_C 256
#define MID 128

typedef float f32x4 __attribute__((ext_vector_type(4)));
typedef __bf16 bf16x8 __attribute__((ext_vector_type(8)));
typedef short short8 __attribute__((ext_vector_type(8)));

__device__ __forceinline__ unsigned short f2bf(float f) {
  unsigned int u = __builtin_bit_cast(unsigned int, f);
  u += 0x7fffu + ((u >> 16) & 1u);   // round-to-nearest-even
  return (unsigned short)(u >> 16);
}

__device__ __forceinline__ float bf2f(unsigned short h) {
  return __builtin_bit_cast(float, (unsigned int)h << 16);
}

// One block per batch. 512 threads = 8 waves.
// Phase 1: x (f32) -> bf16 -> swizzled LDS            (HBM read 256KB/block)
// Phase 2: sim = X X^T via MFMA, sim stays in VGPRs;
//          r2[n] (row sum of squares, via columns by symmetry),
//          smid[m] = sim[mid,m]; v; u[n]; logits; softmax.
// Phase 3: out = p[n] * x  (x from LDS bf16)          (HBM write 256KB/block)
__global__ __launch_bounds__(512, 2) void spat_attn(
    const float* __restrict__ x, const float* __restrict__ kern,
    const float* __restrict__ bias, float* __restrict__ out)
{
  __shared__ __align__(16) unsigned short Xs[B_N * B_C];  // 128 KB, swizzled bf16
  __shared__ float smid[B_N];
  __shared__ float r2s[B_N];
  __shared__ float vb[B_N];
  __shared__ float wlog[B_N];
  __shared__ float wexp[B_N];

  const int b = blockIdx.x;
  const int tid = threadIdx.x;
  const float* __restrict__ xb = x + (size_t)b * (B_N * B_C);

  // ---------------- Phase 1: load + convert + swizzled LDS store ----------
  // Swizzle: row r, 16B-chunk q (8 bf16) stored at chunk (q ^ (r&7)).
  #pragma unroll 4
  for (int i = 0; i < 16; ++i) {
    const int e8 = i * 4096 + tid * 8;
    const float4 f0 = *reinterpret_cast<const float4*>(xb + e8);
    const float4 f1 = *reinterpret_cast<const float4*>(xb + e8 + 4);
    const int r = e8 >> 8;
    const int q = (e8 >> 3) & 31;
    union { unsigned short us[8]; short8 v; } P;
    P.us[0] = f2bf(f0.x); P.us[1] = f2bf(f0.y); P.us[2] = f2bf(f0.z); P.us[3] = f2bf(f0.w);
    P.us[4] = f2bf(f1.x); P.us[5] = f2bf(f1.y); P.us[6] = f2bf(f1.z); P.us[7] = f2bf(f1.w);
    *reinterpret_cast<short8*>(&Xs[(r << 8) + ((q ^ (r & 7)) << 3)]) = P.v;
  }
  __syncthreads();

  // ---------------- Phase 2: sim + reductions -----------------------------
  const int w  = tid >> 6;   // wave 0..7 -> columns [32w, 32w+32)
  const int l  = tid & 63;
  const int lr = l & 15;     // lane row-in-group
  const int g  = l >> 4;     // k-group 0..3
  const int sw = lr & 7;     // row&7 == lr&7 for all frag rows

  f32x4 acc[16][2];
  #pragma unroll
  for (int t = 0; t < 16; ++t) {
    acc[t][0] = {0.f, 0.f, 0.f, 0.f};
    acc[t][1] = {0.f, 0.f, 0.f, 0.f};
  }

  const int rb0 = 32 * w + lr;   // B-frag rows (tile-col 2w)
  const int rb1 = rb0 + 16;      // (tile-col 2w+1)
  #pragma unroll
  for (int kk = 0; kk < 8; ++kk) {
    const int q  = 4 * kk + g;
    const int qs = ((q ^ sw) << 3);
    const bf16x8 b0 = __builtin_bit_cast(bf16x8,
        *reinterpret_cast<const short8*>(&Xs[(rb0 << 8) + qs]));
    const bf16x8 b1 = __builtin_bit_cast(bf16x8,
        *reinterpret_cast<const short8*>(&Xs[(rb1 << 8) + qs]));
    #pragma unroll
    for (int t = 0; t < 16; ++t) {
      const bf16x8 a = __builtin_bit_cast(bf16x8,
          *reinterpret_cast<const short8*>(&Xs[((16 * t + lr) << 8) + qs]));
      acc[t][0] = __builtin_amdgcn_mfma_f32_16x16x32_bf16(a, b0, acc[t][0], 0, 0, 0);
      acc[t][1] = __builtin_amdgcn_mfma_f32_16x16x32_bf16(a, b1, acc[t][1], 0, 0, 0);
    }
  }

  // r2 per column (== per row by exact symmetry); smid = row MID.
  float rp0 = 0.f, rp1 = 0.f;
  #pragma unroll
  for (int t = 0; t < 16; ++t) {
    #pragma unroll
    for (int r = 0; r < 4; ++r) {
      rp0 += acc[t][0][r] * acc[t][0][r];
      rp1 += acc[t][1][r] * acc[t][1][r];
    }
  }
  rp0 += __shfl_xor(rp0, 16); rp0 += __shfl_xor(rp0, 32);
  rp1 += __shfl_xor(rp1, 16); rp1 += __shfl_xor(rp1, 32);
  if (l < 16) {
    r2s[32 * w + l]      = rp0;
    r2s[32 * w + 16 + l] = rp1;
    // row MID=128 lives in tile-row 8, reg 0, k-group 0 (lanes 0..15)
    smid[32 * w + l]      = acc[8][0][0];
    smid[32 * w + 16 + l] = acc[8][1][0];
  }
  __syncthreads();

  if (tid < B_N) {
    const float rinvm = rsqrtf(fmaxf(r2s[MID], 1e-12f));
    vb[tid] = smid[tid] * rinvm * kern[tid];
  }
  __syncthreads();

  // u[n] = sum_m sim[n,m] v[m]  (done over columns by symmetry)
  float up0 = 0.f, up1 = 0.f;
  #pragma unroll
  for (int t = 0; t < 16; ++t) {
    #pragma unroll
    for (int r = 0; r < 4; ++r) {
      const float vv = vb[16 * t + 4 * g + r];
      up0 += acc[t][0][r] * vv;
      up1 += acc[t][1][r] * vv;
    }
  }
  up0 += __shfl_xor(up0, 16); up0 += __shfl_xor(up0, 32);
  up1 += __shfl_xor(up1, 16); up1 += __shfl_xor(up1, 32);
  if (l < 16) {
    const int n0 = 32 * w + l, n1 = n0 + 16;
    wlog[n0] = up0 * rsqrtf(fmaxf(r2s[n0], 1e-12f)) + bias[n0];
    wlog[n1] = up1 * rsqrtf(fmaxf(r2s[n1], 1e-12f)) + bias[n1];
  }
  __syncthreads();

  // softmax over the 256 logits (wave 0)
  if (tid < 64) {
    const float a0 = wlog[tid], a1 = wlog[tid + 64], a2 = wlog[tid + 128], a3 = wlog[tid + 192];
    float mx = fmaxf(fmaxf(a0, a1), fmaxf(a2, a3));
    #pragma unroll
    for (int off = 32; off >= 1; off >>= 1) mx = fmaxf(mx, __shfl_xor(mx, off));
    const float e0 = __expf(a0 - mx), e1 = __expf(a1 - mx), e2 = __expf(a2 - mx), e3 = __expf(a3 - mx);
    float s = e0 + e1 + e2 + e3;
    #pragma unroll
    for (int off = 32; off >= 1; off >>= 1) s += __shfl_xor(s, off);
    const float inv = 1.0f / s;
    wexp[tid] = e0 * inv; wexp[tid + 64] = e1 * inv;
    wexp[tid + 128] = e2 * inv; wexp[tid + 192] = e3 * inv;
  }
  __syncthreads();

  // ---------------- Phase 3: out = p[row] * x (x from LDS bf16) -----------
  float* __restrict__ ob = out + (size_t)b * (B_N * B_C);
  #pragma unroll 4
  for (int i = 0; i < 16; ++i) {
    const int e8 = i * 4096 + tid * 8;
    const int r = e8 >> 8;
    const int q = (e8 >> 3) & 31;
    union { short8 v; unsigned short us[8]; } P;
    P.v = *reinterpret_cast<const short8*>(&Xs[(r << 8) + ((q ^ (r & 7)) << 3)]);
    const float wt = wexp[r];
    float4 o0, o1;
    o0.x = bf2f(P.us[0]) * wt; o0.y = bf2f(P.us[1]) * wt;
    o0.z = bf2f(P.us[2]) * wt; o0.w = bf2f(P.us[3]) * wt;
    o1.x = bf2f(P.us[4]) * wt; o1.y = bf2f(P.us[5]) * wt;
    o1.z = bf2f(P.us[6]) * wt; o1.w = bf2f(P.us[7]) * wt;
    *reinterpret_cast<float4*>(ob + e8)     = o0;
    *reinterpret_cast<float4*>(ob + e8 + 4) = o1;
  }
}

extern "C" void kernel_launch(void* const* d_in, const int* in_sizes, int n_in,
                              void* d_out, int out_size, void* d_ws, size_t ws_size,
                              hipStream_t stream) {
  const float* x    = (const float*)d_in[0];
  const float* kern = (const float*)d_in[1];
  const float* bias = (const float*)d_in[2];
  float* out = (float*)d_out;
  const int nb = in_sizes[0] / (B_N * B_C);   // 512 batches
  spat_attn<<<dim3(nb), dim3(512), 0, stream>>>(x, kern, bias, out);
}